// Round 4
// baseline (191.163 us; speedup 1.0000x reference)
//
#include <hip/hip_runtime.h>
#include <hip/hip_bf16.h>
#include <cstdint>

// Problem (all inputs/outputs fp32):
//   out[8192][2048] = X[8192][2048] @ Weff[2048][2048]
//   Weff[k][n] = W[k][n] + SCALE * sum_r A[k][r]*Bk[r][n], SCALE = 4/4 = 1.0
//
// Pipeline (2 launches):
//   prep_all: [blocks 0..8191] fp32 X -> bf16 Xb (d_ws)
//             [blocks 8192..9215] fp32 (W + A@Bk)^T -> bf16 Wt [N][K]
//   gemm_8ph: 256x256 tile, BK=64, 8 waves (2Mx4N), ROTATED 8-phase.
//
// R3 post-mortem: reads->barrier->lgkm0->MFMA SERIALIZES LDS pipe vs MFMA
// pipe: iter = reads(4600 cyc/CU) + MFMA(4966 cyc/SIMD) + barriers ~= 10.6k
// measured. Fix: ROTATE -- phase p executes MMA(p-1) (frags read last
// phase), then issues reads(p). Reads drain under the next phase's MFMA.
// MMA-before-read keeps register reuse WAR-safe (consumed at issue): no
// extra frag buffers (we are pinned at 128 arch + 128 acc = 256/wave).
// Explicit lgkmcnt(0) dropped -- compiler inserts fine-grained waits for
// the reg deps (G7). One barrier per phase (orderings below). sched_barrier
// after each MMA pins MMA-before-reads (prevents fragment renaming).
//
// Rotated ledger (stage slots s1..s8 load tiles 2j+2 (kn0), 2j+3 (kn1);
// 2 loads each; reads(p) feed MMA at p+1):
//   phase : MMA        reads              stage         wait
//   P2    : q00 buf0   B1/buf0->b1        --            --
//   P3    : q01 buf0   A1/buf0->a         s1=buf0.B0    --
//   P4    : q11 buf0   --                 s2=buf0.A0    --
//   P5    : q10 buf0   A0,B0/buf1->a,b0   s3=buf0.B1    VMW(6)
//   P6    : q00 buf1   B1/buf1->b1        s4=buf0.A1    --
//   P7    : q01 buf1   A1/buf1->a         s5=B0,s6=A0/buf1  VMW(8)
//   P8    : q11 buf1   --                 s7=buf1.B1    --
//   P1'   : q10 buf1   A0,B0/buf0->a,b0   s8=buf1.A1    VMW(6)
// Steady FIFO: enter P2 with {s5,s6,s7,s8}(j-1)=8 outstanding.
//   VMW(6)@P5 drains s5,s6,s7(j-1) (issued 5-6 phases prior) -> publishes
//     P5/P6 reads. VMW(8)@P7 drains s8(j-1) (6 phases) -> P7 read.
//   VMW(6)@P1' drains s1..s4(j) (3-6 phases) -> P1'/P2'/P3' reads.
// WAR: every region restaged >= 2 phases after its last ds_read's consuming
//   MMA; single barrier/phase gives the happens-before chain (read completes
//   before reader's next-phase MMA finishes -> before BAR(p+2) crossing ->
//   before stage issue at >= p+2).
// Prologue stages buf0{B0,A0,B1,A1}+buf1{B0,A0,B1} (14 loads), VMW(6)
//   publishes buf0, then reads A0,B0 and stages buf1.A1 -> identical FIFO
//   state to steady. Peeled last iter: VMW(4)@P5, VMW(0)@P6, stores by
//   quadrant at P6..P9 (q00,q01,q11,q10) with no vm-waits after stores.
// Round-4 lesson kept: do NOT read fp32 X inside the gemm.

using bf16 = __hip_bfloat16;
typedef __attribute__((ext_vector_type(8))) __bf16 bf16x8;
typedef __attribute__((ext_vector_type(4))) float f32x4;

constexpr int Mdim = 8192;   // B*S
constexpr int Ndim = 2048;   // NH*HD
constexpr int Kdim = 2048;   // H
constexpr float SCALE = 1.0f;  // ALPHA/RANK = 4/4

constexpr int BM = 256, BN = 256, BK = 64;
constexpr int NT2 = Kdim / (2 * BK);                   // 16 iterations
constexpr int CVT_BLOCKS = (Mdim * Kdim) / (256 * 8);  // 8192
constexpr int PREP_BLOCKS = (Ndim / 64) * (Kdim / 64); // 1024

__device__ __forceinline__ void gload_lds16(const void* g, void* l) {
  __builtin_amdgcn_global_load_lds(
      (const __attribute__((address_space(1))) uint32_t*)g,
      (__attribute__((address_space(3))) uint32_t*)l,
      16, 0, 0);
}

// ------------- prep_all: cvt_x (blocks<8192) + Weff^T build --------------
__global__ void prep_all(const float* __restrict__ X,
                         const float* __restrict__ W,
                         const float* __restrict__ A,
                         const float* __restrict__ Bk,
                         uint16_t* __restrict__ Xb,
                         uint16_t* __restrict__ Wt) {
  __shared__ float tile[64][65];  // used by prep part only (+1 pad)

  if (blockIdx.x < CVT_BLOCKS) {
    // ---- fp32 -> bf16, 8 elems/thread, float4 loads ----
    const int i = blockIdx.x * blockDim.x + threadIdx.x;
    const float4* Xv = (const float4*)X;
    float4 a = Xv[i * 2 + 0];
    float4 b = Xv[i * 2 + 1];
    uint16_t o[8];
    o[0] = __bfloat16_as_ushort(__float2bfloat16(a.x));
    o[1] = __bfloat16_as_ushort(__float2bfloat16(a.y));
    o[2] = __bfloat16_as_ushort(__float2bfloat16(a.z));
    o[3] = __bfloat16_as_ushort(__float2bfloat16(a.w));
    o[4] = __bfloat16_as_ushort(__float2bfloat16(b.x));
    o[5] = __bfloat16_as_ushort(__float2bfloat16(b.y));
    o[6] = __bfloat16_as_ushort(__float2bfloat16(b.z));
    o[7] = __bfloat16_as_ushort(__float2bfloat16(b.w));
    *reinterpret_cast<uint4*>(Xb + (size_t)i * 8) = *reinterpret_cast<uint4*>(o);
  } else {
    // ---- Weff^T = (W + A@Bk)^T, [N][K] bf16 ----
    const int pid = blockIdx.x - CVT_BLOCKS;       // 0..1023
    const int tx = threadIdx.x & 63;
    const int ty = threadIdx.x >> 6;
    const int n0 = (pid & 31) * 64, k0 = (pid >> 5) * 64;

    const int n = n0 + tx;
    const float b0 = Bk[0 * Ndim + n];
    const float b1 = Bk[1 * Ndim + n];
    const float b2 = Bk[2 * Ndim + n];
    const float b3 = Bk[3 * Ndim + n];

    for (int i = ty; i < 64; i += 4) {
      const int k = k0 + i;
      float w = W[(size_t)k * Ndim + n];
      w += SCALE * (A[k * 4 + 0] * b0 + A[k * 4 + 1] * b1 +
                    A[k * 4 + 2] * b2 + A[k * 4 + 3] * b3);
      tile[tx][i] = w;                       // transposed into LDS
    }
    __syncthreads();
    for (int i = ty; i < 64; i += 4) {
      Wt[(size_t)(n0 + i) * Kdim + (k0 + tx)] =
          __bfloat16_as_ushort(__float2bfloat16(tile[i][tx]));
    }
  }
}

// ---------------- main GEMM: C = Xb @ Weff (Wt is Weff^T, K-major) --------
#define FENCE() asm volatile("" ::: "memory")
#define VMW(N)  asm volatile("s_waitcnt vmcnt(" #N ")" ::: "memory")
#define PH()                                                                   \
  do {                                                                         \
    FENCE();                                                                   \
    __builtin_amdgcn_s_barrier();                                              \
    FENCE();                                                                   \
  } while (0)

__global__ __launch_bounds__(512, 2) void gemm_8ph(
    const uint16_t* __restrict__ X, const uint16_t* __restrict__ Wt,
    float* __restrict__ out) {
  // LDS: [A0 | B0 | A1 | B1], 16384 uint16 each = 128 KiB total.
  __shared__ uint16_t lds[65536];

  const int t = threadIdx.x;
  const int wave = t >> 6, lane = t & 63;
  const int wm = wave >> 2, wn = wave & 3;   // 2 x 4 wave grid
  const int l15 = lane & 15, kg = lane >> 4;
  const int sw = l15 & 7;

  // Bijective XCD patch swizzle: 256 blocks, 8 XCDs x 32 blocks.
  const int lid = blockIdx.x;                 // 0..255
  const int xcd = lid & 7, loc = lid >> 3;    // loc 0..31
  const int by = xcd * 4 + (loc & 3);         // 0..31
  const int bx = loc >> 2;                    // 0..7
  const int m0 = by * BM, n0 = bx * BN;

  const uint16_t* Ag = X + (size_t)m0 * Kdim;
  const uint16_t* Bg = Wt + (size_t)n0 * Kdim;

  // staging geometry: slot = 8 rows x 64 cols (1 KB); wave w owns slots
  // {2w, 2w+1} of each 128-row half-tile. Source chunk col is XOR-swizzled
  // so the linear LDS dest holds phys chunk p = c ^ (row&7).
  const int r8 = lane >> 3;
  const int gc = (lane & 7) ^ r8;
  const int slot0 = wave * 2, slot1 = slot0 + 1;
  const size_t go0 = (size_t)(slot0 * 8 + r8) * Kdim + gc * 8;
  const size_t go1 = (size_t)(slot1 * 8 + r8) * Kdim + gc * 8;

  // per-lane LDS element offsets for frag reads (per k-step s2)
  int aE[2], bE[2];
#pragma unroll
  for (int s2 = 0; s2 < 2; ++s2) {
    const int p = (s2 * 4 + kg) ^ sw;
    aE[s2] = (wm * 64 + l15) * 64 + p * 8;
    bE[s2] = (wn * 32 + l15) * 64 + p * 8;
  }

#define STAGE_A(buf, h, kt)                                                    \
  do {                                                                         \
    gload_lds16(Ag + go0 + (size_t)(h) * 128 * Kdim + (kt),                    \
                &lds[(buf) * 32768 + (h) * 8192 + slot0 * 512]);               \
    gload_lds16(Ag + go1 + (size_t)(h) * 128 * Kdim + (kt),                    \
                &lds[(buf) * 32768 + (h) * 8192 + slot1 * 512]);               \
  } while (0)
#define STAGE_B(buf, h, kt)                                                    \
  do {                                                                         \
    gload_lds16(Bg + go0 + (size_t)(h) * 128 * Kdim + (kt),                    \
                &lds[(buf) * 32768 + 16384 + (h) * 8192 + slot0 * 512]);       \
    gload_lds16(Bg + go1 + (size_t)(h) * 128 * Kdim + (kt),                    \
                &lds[(buf) * 32768 + 16384 + (h) * 8192 + slot1 * 512]);       \
  } while (0)

  bf16x8 a[4][2], b0[2][2], b1[2][2];
  f32x4 acc[8][4] = {};

#define READ_A(QM, buf)                                                        \
  do {                                                                         \
    _Pragma("unroll") for (int ii = 0; ii < 4; ++ii)                           \
        _Pragma("unroll") for (int s2 = 0; s2 < 2; ++s2)                       \
            a[ii][s2] = *reinterpret_cast<const bf16x8*>(                      \
                &lds[(buf) * 32768 + (QM) * 8192 + ii * 1024 + aE[s2]]);       \
  } while (0)
#define READ_B(QN, buf, dst)                                                   \
  do {                                                                         \
    _Pragma("unroll") for (int jj = 0; jj < 2; ++jj)                           \
        _Pragma("unroll") for (int s2 = 0; s2 < 2; ++s2)                       \
            dst[jj][s2] = *reinterpret_cast<const bf16x8*>(                    \
                &lds[(buf) * 32768 + 16384 + (QN) * 8192 + jj * 1024 +         \
                     bE[s2]]);                                                 \
  } while (0)
// MMA uses the fragments read LAST phase; sched_barrier(0) afterwards pins
// MMA-before-reads so the allocator reuses frag regs in place (no rename).
#define MMA(QM, QN, barr)                                                      \
  do {                                                                         \
    __builtin_amdgcn_s_setprio(1);                                             \
    _Pragma("unroll") for (int s2 = 0; s2 < 2; ++s2)                           \
        _Pragma("unroll") for (int ii = 0; ii < 4; ++ii)                       \
            _Pragma("unroll") for (int jj = 0; jj < 2; ++jj)                   \
                acc[(QM) * 4 + ii][(QN) * 2 + jj] =                            \
                    __builtin_amdgcn_mfma_f32_16x16x32_bf16(                   \
                        a[ii][s2], barr[jj][s2],                               \
                        acc[(QM) * 4 + ii][(QN) * 2 + jj], 0, 0, 0);           \
    __builtin_amdgcn_s_setprio(0);                                             \
    __builtin_amdgcn_sched_barrier(0);                                         \
  } while (0)
// store one 128x128 output quadrant (this wave's 64x32 piece of it)
#define STORE_Q(QM, QN)                                                        \
  do {                                                                         \
    _Pragma("unroll") for (int ii = 0; ii < 4; ++ii) {                         \
      const int mb = m0 + (QM) * 128 + wm * 64 + ii * 16 + kg * 4;             \
      _Pragma("unroll") for (int jj = 0; jj < 2; ++jj) {                       \
        const int n = n0 + (QN) * 128 + wn * 32 + jj * 16 + l15;               \
        _Pragma("unroll") for (int r = 0; r < 4; ++r)                          \
            out[(size_t)(mb + r) * Ndim + n] =                                 \
                acc[(QM) * 4 + ii][(QN) * 2 + jj][r];                          \
      }                                                                        \
    }                                                                          \
  } while (0)

  // ---- prologue: buf0{B0,A0,B1,A1}, buf1{B0,A0,B1} (FIFO order matters) ----
  STAGE_B(0, 0, 0); STAGE_A(0, 0, 0); STAGE_B(0, 1, 0); STAGE_A(0, 1, 0);
  FENCE();
  STAGE_B(1, 0, BK); STAGE_A(1, 0, BK); STAGE_B(1, 1, BK);
  FENCE();
  // "P1(0)": publish buf0; read A0,B0; stage s8(-1)=buf1.A1. No MMA.
  VMW(6); PH();
  READ_A(0, 0); READ_B(0, 0, b0);
  STAGE_A(1, 1, BK);

  // ---- steady loop: full iterations j = 0 .. NT2-2 ----
#pragma unroll 1
  for (int j = 0; j < NT2 - 1; ++j) {
    const int kn0 = j * 128 + 128;   // tile 2j+2 -> buf0
    const int kn1 = j * 128 + 192;   // tile 2j+3 -> buf1

    // P2
    PH(); MMA(0, 0, b0); READ_B(1, 0, b1);
    // P3
    PH(); MMA(0, 1, b1); READ_A(1, 0); STAGE_B(0, 0, kn0);          // s1
    // P4
    PH(); MMA(1, 1, b1); STAGE_A(0, 0, kn0);                        // s2
    // P5
    VMW(6); PH(); MMA(1, 0, b0);
    READ_A(0, 1); READ_B(0, 1, b0); STAGE_B(0, 1, kn0);             // s3
    // P6
    PH(); MMA(0, 0, b0); READ_B(1, 1, b1); STAGE_A(0, 1, kn0);      // s4
    // P7
    VMW(8); PH(); MMA(0, 1, b1);
    READ_A(1, 1); STAGE_B(1, 0, kn1); STAGE_A(1, 0, kn1);           // s5,s6
    // P8
    PH(); MMA(1, 1, b1); STAGE_B(1, 1, kn1);                        // s7
    // P1'
    VMW(6); PH(); MMA(1, 0, b0);
    READ_A(0, 0); READ_B(0, 0, b0); STAGE_A(1, 1, kn1);             // s8
  }

  // ---- peeled last iteration (tiles 30/31): no staging; stores overlap ----
  // P2
  PH(); MMA(0, 0, b0); READ_B(1, 0, b1);
  // P3
  PH(); MMA(0, 1, b1); READ_A(1, 0);
  // P4
  PH(); MMA(1, 1, b1);
  // P5: publish buf1.{B0,A0} (s5,s6 issued 6 phases ago -> free)
  VMW(4); PH(); MMA(1, 0, b0); READ_A(0, 1); READ_B(0, 1, b0);
  // P6: drain s7,s8 (issued >=5 phases ago); stores begin, no vm-waits after
  VMW(0); PH(); MMA(0, 0, b0); READ_B(1, 1, b1); STORE_Q(0, 0);
  // P7
  PH(); MMA(0, 1, b1); READ_A(1, 1); STORE_Q(0, 1);
  // P8
  PH(); MMA(1, 1, b1); STORE_Q(1, 1);
  // P9
  PH(); MMA(1, 0, b0); STORE_Q(1, 0);

#undef STAGE_A
#undef STAGE_B
#undef READ_A
#undef READ_B
#undef MMA
#undef STORE_Q
}

extern "C" void kernel_launch(void* const* d_in, const int* in_sizes, int n_in,
                              void* d_out, int out_size, void* d_ws, size_t ws_size,
                              hipStream_t stream) {
  const float* x  = (const float*)d_in[0];  // [4,2048,2048]
  const float* W  = (const float*)d_in[1];  // [2048,16,128]
  const float* A  = (const float*)d_in[2];  // [2048,4]
  const float* Bk = (const float*)d_in[3];  // [4,16,128]
  float* out = (float*)d_out;               // [4,2048,16,128] fp32

  uint16_t* Xb = (uint16_t*)d_ws;                               // 32 MB
  uint16_t* Wt = (uint16_t*)((char*)d_ws + (size_t)Mdim * Kdim * 2);  // 8 MB

  // fused: X fp32->bf16  +  Weff^T build
  prep_all<<<CVT_BLOCKS + PREP_BLOCKS, 256, 0, stream>>>(x, W, A, Bk, Xb, Wt);

  // main GEMM: 256 blocks (1/CU), 512 threads, rotated 8-phase schedule
  gemm_8ph<<<(Mdim / BM) * (Ndim / BN), 512, 0, stream>>>(Xb, Wt, out);
}